// Round 4
// baseline (267.470 us; speedup 1.0000x reference)
//
#include <hip/hip_runtime.h>
#include <hip/hip_bf16.h>
#include <math.h>

#define L_DIM 4096
#define H_DIM 512
#define B_DIM 8
#define SEG 2048

typedef __attribute__((ext_vector_type(8))) short short8;
typedef __attribute__((ext_vector_type(4))) float floatx4;

__device__ __forceinline__ unsigned f2bf(float f) {
    unsigned x = __float_as_uint(f);
    return (x + 0x7fffu + ((x >> 16) & 1u)) >> 16;   // RNE, finite inputs only
}

// ---------------------------------------------------------------------------
// Stage 1 (MFMA): causal Toeplitz conv + D-skip + exact GELU.
// Round-11: rounds 9-10 failed because the scheduler sank the batched loads
// back to their uses (VGPR stayed 68 -> load->use distance ~1 -> latency
// bound, MfmaUtil 22%). Fix: sched_barrier(0) fence between the 23-frag
// batch load and the 64-MFMA cluster -- the scheduler cannot sink loads
// past it, forcing the batch live in registers (~124 VGPR, under the 170
// cap at 3 waves/EU). Loads ordered earliest-use-first (Bs0, As7..14, then
// (Bsk, As7-k) pairs) so dependence tracking emits counted lgkmcnt and the
// MFMA cluster starts before the last loads land. Next group's loads sit
// in the same scheduling region as this group's MFMAs -> prefetch overlap.
// ---------------------------------------------------------------------------
__global__ __launch_bounds__(256, 3) void conv_gelu_mfma(
    const float* __restrict__ u,    // (B,H,L) fp32
    const float* __restrict__ kk,   // (C=1,H,L) fp32
    const float* __restrict__ Dp,   // (H) fp32
    unsigned short* __restrict__ g, // (B,H,L) bf16 out (workspace)
    const float* __restrict__ W,    // (H,H) fp32
    unsigned short* __restrict__ Wb)// (H,H) bf16 out (workspace tail), may be null
{
    __shared__ __align__(16) unsigned short kA[4144];
    __shared__ __align__(16) unsigned short kB[4144];
    __shared__ __align__(16) unsigned short us[8][2104];

    const int h   = blockIdx.x;
    const int Lb  = blockIdx.y << 10;        // l-chunk base
    const int tid = threadIdx.x;
    const int lane = tid & 63;
    const int w   = tid >> 6;                // wave id 0..3
    const int i   = lane & 15;               // A-row / C-col index
    const int q   = lane >> 4;               // quad
    const int b   = i & 7;                   // batch   (C-col decode)
    const int s   = i >> 3;                  // l-tile  (C-col decode)

    // one-time W fp32 -> bf16 conversion (coalesced, one row per h-block)
    if (Wb != nullptr && blockIdx.y == 0) {
        const float* wsrc = W + (size_t)h * H_DIM;
        unsigned short* wdst = Wb + (size_t)h * H_DIM;
        wdst[tid]       = (unsigned short)f2bf(wsrc[tid]);
        wdst[tid + 256] = (unsigned short)f2bf(wsrc[tid + 256]);
    }

    const float* kh = kk + (size_t)h * L_DIM;

    for (int p = tid; p < 4144; p += 256) {
        int t1 = L_DIM + 15 - p;
        int t2 = L_DIM + 14 - p;
        float v1 = (t1 >= 0 && t1 < L_DIM) ? kh[t1] : 0.0f;
        float v2 = (t2 >= 0 && t2 < L_DIM) ? kh[t2] : 0.0f;
        kA[p] = (unsigned short)f2bf(v1);
        kB[p] = (unsigned short)f2bf(v2);
    }

    floatx4 acc[8];
    #pragma unroll
    for (int t = 0; t < 8; t++) acc[t] = (floatx4){0.f, 0.f, 0.f, 0.f};

    const char* kbase = (const char*)((i & 1) ? kA : kB);
    const int aconst = 2 * (L_DIM + ((i & 1) ? 15 : 14) - i + 8 * q);
    const int basew = Lb + 32 * w;           // l0(t) = basew + 128*t

    union AFrag { int x[4]; short8 v; };

    for (int seg = 0; seg < 2; seg++) {
        const int ms = seg * SEG;
        const int mstart = (seg == 0) ? -32 : SEG;
        const int segmax = ms + SEG - 32;
        if (seg == 1) {
            if (Lb + 992 < SEG) break;       // uniform per block
            __syncthreads();                 // protect us[] until seg-0 compute done
        }
        for (int e = tid * 4; e < 2096; e += 1024) {
            int m = ms - 32 + e;
            #pragma unroll
            for (int bb = 0; bb < 8; bb++) {
                float4 v = make_float4(0.f, 0.f, 0.f, 0.f);
                if (m >= 0 && m < L_DIM)
                    v = *(const float4*)(u + ((size_t)bb * H_DIM + h) * L_DIM + m);
                unsigned lo = f2bf(v.x) | (f2bf(v.y) << 16);
                unsigned hi = f2bf(v.z) | (f2bf(v.w) << 16);
                *(uint2*)&us[bb][e] = make_uint2(lo, hi);
            }
        }
        __syncthreads();

        const char* bbase = (const char*)&us[b][0] + 2 * (32 - ms + 16 * s + 8 * q);
        const char* ab = kbase + aconst;     // A-frag address at dd = 0

        for (int c = 0; c < 4; c++) {
            const int c32 = 32 * c;
            const int rel = basew - c32;
            // m0(j) = rel - 128*j must lie in [mstart, segmax]
            const int j_hi = (rel - mstart) >> 7;            // floor div
            int j_lo = (rel - segmax + 127) >> 7;            // ceil div
            if (j_lo < -7) j_lo = -7;                        // t<=7 bound
            if (j_hi < j_lo) continue;
            const int n = j_hi - j_lo + 1;
            // iterations with j >= 0 (dd always >= 0 there)
            int n_pos = 0;
            if (j_hi >= 0) n_pos = j_hi - ((j_lo > 0) ? j_lo : 0) + 1;
            const int n_main = n_pos & ~7;

            const char* abase = ab - 2 * c32;                // Abar[sig] at abase - 256*sig
            const char* bb0 = bbase + 2 * (rel - 128 * j_hi);// Bbar[u]  at bb0 + 256*u

            // ---- main loop: groups of 8 sub-steps, batched register tiles
            for (int jb = 0; jb < n_main; jb += 8) {
                const int j_g = j_hi - jb;
                const char* aptr = abase - 256 * (j_g + 7);  // As[d] at aptr + 256*(14-d)
                const char* bptr = bb0 + 256 * jb;

                AFrag As[15];
                short8 Bs[8];
                // earliest-use-first load order: k=0 needs As[7..14], Bs[0];
                // each further k adds Bs[k], As[7-k].
                Bs[0] = *(const short8*)(bptr);
                #pragma unroll
                for (int d = 7; d < 15; d++) {
                    const int* ap = (const int*)(aptr + 256 * (14 - d));
                    As[d].x[0] = ap[0]; As[d].x[1] = ap[1];
                    As[d].x[2] = ap[2]; As[d].x[3] = ap[3];
                }
                #pragma unroll
                for (int k = 1; k < 8; k++) {
                    Bs[k] = *(const short8*)(bptr + 256 * k);
                    const int* ap = (const int*)(aptr + 256 * (14 - (7 - k)));
                    As[7 - k].x[0] = ap[0]; As[7 - k].x[1] = ap[1];
                    As[7 - k].x[2] = ap[2]; As[7 - k].x[3] = ap[3];
                }
                // fence: loads may not sink below, MFMAs may not hoist above
                __builtin_amdgcn_sched_barrier(0);

                #pragma unroll
                for (int k = 0; k < 8; k++)
                    #pragma unroll
                    for (int t = 0; t < 8; t++)
                        acc[t] = __builtin_amdgcn_mfma_f32_16x16x32_bf16(
                            As[7 - k + t].v, Bs[k], acc[t], 0, 0, 0);
            }

            // ---- guarded tail: partial group + negative-j band edge (<= 14 iters)
            if (n_main < n) {
                const int j_top = j_hi - n_main;
                AFrag Wd[8];
                #pragma unroll
                for (int d = 1; d < 8; d++) {
                    const int dd = c32 + (j_top + d) * 128;
                    if (dd >= 0) {
                        const int* ap = (const int*)(ab - 2 * dd);
                        Wd[d].x[0] = ap[0]; Wd[d].x[1] = ap[1];
                        Wd[d].x[2] = ap[2]; Wd[d].x[3] = ap[3];
                    } else {
                        Wd[d].x[0] = 0; Wd[d].x[1] = 0; Wd[d].x[2] = 0; Wd[d].x[3] = 0;
                    }
                }
                for (int jb = n_main; jb < n; jb += 8) {
                    #pragma unroll
                    for (int k = 0; k < 8; k++) {
                        const int jj = jb + k;
                        if (jj < n) {
                            const int dd0 = c32 + (j_hi - jj) * 128;
                            AFrag nf;
                            if (dd0 >= 0) {
                                const int* ap = (const int*)(ab - 2 * dd0);
                                nf.x[0] = ap[0]; nf.x[1] = ap[1];
                                nf.x[2] = ap[2]; nf.x[3] = ap[3];
                            } else {
                                nf.x[0] = 0; nf.x[1] = 0; nf.x[2] = 0; nf.x[3] = 0;
                            }
                            Wd[(8 - k) & 7] = nf;
                            short8 bf = *(const short8*)(bb0 + 256 * jj);
                            #pragma unroll
                            for (int t = 0; t < 8; t++)
                                acc[t] = __builtin_amdgcn_mfma_f32_16x16x32_bf16(
                                    Wd[(t - k) & 7].v, bf, acc[t], 0, 0, 0);
                        }
                    }
                }
            }
        }
    }

    const float Dh = Dp[h];
    #pragma unroll
    for (int t = 0; t < 8; t++) {
        const int l0 = Lb + 32 * w + 128 * t;
        const int lb2 = l0 + 16 * s + 4 * q;          // C/D: row = 4q + r, col = (b,s)
        const size_t off = ((size_t)b * H_DIM + h) * L_DIM + lb2;
        float4 uv = *(const float4*)(u + off);
        float y0 = acc[t][0] + uv.x * Dh;
        float y1 = acc[t][1] + uv.y * Dh;
        float y2 = acc[t][2] + uv.z * Dh;
        float y3 = acc[t][3] + uv.w * Dh;
        const float c = 0.70710678118654752f;
        float g0 = 0.5f * y0 * (1.0f + erff(y0 * c));
        float g1 = 0.5f * y1 * (1.0f + erff(y1 * c));
        float g2 = 0.5f * y2 * (1.0f + erff(y2 * c));
        float g3 = 0.5f * y3 * (1.0f + erff(y3 * c));
        unsigned lo = f2bf(g0) | (f2bf(g1) << 16);
        unsigned hi = f2bf(g2) | (f2bf(g3) << 16);
        *(uint2*)(g + off) = make_uint2(lo, hi);
    }
}

// ---------------------------------------------------------------------------
// Stage 2 (MFMA v2): out[b,d,l] = sum_c W[d,c]*g[b,c,l] + bias[d], fp32 out.
// Round-11: ws row stride 72 -> 76 shorts. At stride 72 the B-frag
// ds_read_b128 bank index is (8(n+q))%32 -> 64 lanes hit only 16 of 32
// banks (16 lanes per 4-bank group) -> 2x LDS slowdown on the bfr reads.
// Stride 76 gives bank (6n+4q)%32, all n distinct -> full bandwidth.
// LDS total 57344 B, still 2 blocks/CU. PREW path unchanged.
// ---------------------------------------------------------------------------
template <bool PREW>
__global__ __launch_bounds__(256, 2) void pointwise_mfma(
    const unsigned short* __restrict__ g,  // (B,H,L) bf16 (workspace)
    const unsigned short* __restrict__ Wb, // (H,H) bf16 (workspace tail) if PREW
    const float* __restrict__ W,           // (H,H) fp32 row-major [d][c]
    const float* __restrict__ bias,        // (H) fp32
    float* __restrict__ out)               // (B,H,L) fp32
{
    __shared__ __align__(16) unsigned gs2[128 * 36];        // 18432 B
    __shared__ __align__(16) unsigned short ws[256 * 76];   // 38912 B

    const int tid = threadIdx.x;
    const int l0 = blockIdx.x * 128;
    const int d0 = blockIdx.y * 256;
    const int bz = blockIdx.z;
    const int w  = tid >> 6;
    const int lane = tid & 63;
    const int n  = lane & 15;      // MFMA row/col lane index
    const int q  = lane >> 4;      // quad

    const int p   = tid & 31;      // c-pair column for g staging
    const int oct = tid >> 5;      // l-16-group 0..7 for g staging

    const int quarter = tid & 3;   // c-quarter for W staging
    const int rb      = tid >> 2;  // d-row base 0..63 for W staging

    floatx4 acc[8][4];
    #pragma unroll
    for (int mt = 0; mt < 8; mt++)
        #pragma unroll
        for (int nt = 0; nt < 4; nt++) acc[mt][nt] = (floatx4){0.f, 0.f, 0.f, 0.f};

    for (int c0 = 0; c0 < H_DIM; c0 += 64) {
        // ---- stage g tile (transpose-pack): rows c0+2p/+1, l = l0+16*oct+0..15
        {
            const unsigned short* gp = g + ((size_t)bz * H_DIM + c0 + 2 * p) * L_DIM + l0 + 16 * oct;
            uint4 va0 = *(const uint4*)gp;
            uint4 va1 = *(const uint4*)(gp + 8);
            uint4 vb0 = *(const uint4*)(gp + L_DIM);
            uint4 vb1 = *(const uint4*)(gp + L_DIM + 8);
            #pragma unroll
            for (int half = 0; half < 2; half++) {
                const unsigned* ua = (const unsigned*)(half ? &va1 : &va0);
                const unsigned* ub = (const unsigned*)(half ? &vb1 : &vb0);
                #pragma unroll
                for (int e = 0; e < 4; e++) {
                    unsigned w0 = (ua[e] & 0xFFFFu) | (ub[e] << 16);        // l even
                    unsigned w1 = (ua[e] >> 16) | (ub[e] & 0xFFFF0000u);    // l odd
                    const int lrow = 16 * oct + 8 * half + 2 * e;
                    gs2[lrow * 36 + p] = w0;
                    gs2[(lrow + 1) * 36 + p] = w1;
                }
            }
        }
        // ---- stage W tile: rows rb+64*gg, c = 16*quarter..+15
        if (PREW) {
            #pragma unroll
            for (int gg = 0; gg < 4; gg++) {
                const int row = rb + 64 * gg;
                const unsigned short* wp = Wb + (size_t)(d0 + row) * H_DIM + c0 + 16 * quarter;
                uint4 w0 = ((const uint4*)wp)[0];
                uint4 w1 = ((const uint4*)wp)[1];
                *(uint4*)&ws[row * 76 + 16 * quarter]     = w0;
                *(uint4*)&ws[row * 76 + 16 * quarter + 8] = w1;
            }
        } else {
            #pragma unroll
            for (int gg = 0; gg < 4; gg++) {
                const int row = rb + 64 * gg;
                const float* wp = W + (size_t)(d0 + row) * H_DIM + c0 + 16 * quarter;
                float4 f0 = ((const float4*)wp)[0];
                float4 f1 = ((const float4*)wp)[1];
                float4 f2 = ((const float4*)wp)[2];
                float4 f3 = ((const float4*)wp)[3];
                unsigned o0 = f2bf(f0.x) | (f2bf(f0.y) << 16);
                unsigned o1 = f2bf(f0.z) | (f2bf(f0.w) << 16);
                unsigned o2 = f2bf(f1.x) | (f2bf(f1.y) << 16);
                unsigned o3 = f2bf(f1.z) | (f2bf(f1.w) << 16);
                unsigned o4 = f2bf(f2.x) | (f2bf(f2.y) << 16);
                unsigned o5 = f2bf(f2.z) | (f2bf(f2.w) << 16);
                unsigned o6 = f2bf(f3.x) | (f2bf(f3.y) << 16);
                unsigned o7 = f2bf(f3.z) | (f2bf(f3.w) << 16);
                *(uint4*)&ws[row * 76 + 16 * quarter]     = make_uint4(o0, o1, o2, o3);
                *(uint4*)&ws[row * 76 + 16 * quarter + 8] = make_uint4(o4, o5, o6, o7);
            }
        }
        __syncthreads();

        // ---- compute: 2 K-steps of 32; per wave 8 mt x 4 nt MFMAs per step
        #pragma unroll
        for (int ks = 0; ks < 2; ks++) {
            short8 bfr[4];
            #pragma unroll
            for (int nt = 0; nt < 4; nt++)
                bfr[nt] = *(const short8*)&ws[(64 * w + 16 * nt + n) * 76 + 32 * ks + 8 * q];
            #pragma unroll
            for (int mt = 0; mt < 8; mt++) {
                union { uint4 u4; short8 v; } af;
                af.u4 = *(const uint4*)&gs2[(16 * mt + n) * 36 + 16 * ks + 4 * q];
                #pragma unroll
                for (int nt = 0; nt < 4; nt++)
                    acc[mt][nt] = __builtin_amdgcn_mfma_f32_16x16x32_bf16(af.v, bfr[nt], acc[mt][nt], 0, 0, 0);
            }
        }
        __syncthreads();
    }

    // ---- epilogue: bias + coalesced float4 stores (4 consecutive l per lane)
    #pragma unroll
    for (int nt = 0; nt < 4; nt++) {
        const int d = d0 + 64 * w + 16 * nt + n;
        const float bb = bias[d];
        float* obase = out + ((size_t)bz * H_DIM + d) * L_DIM + l0 + 4 * q;
        #pragma unroll
        for (int mt = 0; mt < 8; mt++) {
            float4 r = make_float4(acc[mt][nt][0] + bb, acc[mt][nt][1] + bb,
                                   acc[mt][nt][2] + bb, acc[mt][nt][3] + bb);
            *(float4*)(obase + 16 * mt) = r;
        }
    }
}

extern "C" void kernel_launch(void* const* d_in, const int* in_sizes, int n_in,
                              void* d_out, int out_size, void* d_ws, size_t ws_size,
                              hipStream_t stream) {
    const float* u    = (const float*)d_in[0]; // (B,H,L)
    const float* k    = (const float*)d_in[1]; // (C,H,L) C=1
    const float* D    = (const float*)d_in[2]; // (C,H)
    const float* W    = (const float*)d_in[3]; // (H,C*H)
    const float* bias = (const float*)d_in[4]; // (H)
    float* out = (float*)d_out;
    unsigned short* g = (unsigned short*)d_ws;  // (B,H,L) bf16 intermediate, 32 MiB

    const size_t g_bytes = (size_t)B_DIM * H_DIM * L_DIM * sizeof(unsigned short); // 32 MiB
    const size_t w_bytes = (size_t)H_DIM * H_DIM * sizeof(unsigned short);         // 512 KiB
    const bool prew = ws_size >= g_bytes + w_bytes;
    unsigned short* Wb = prew ? (unsigned short*)((char*)d_ws + g_bytes) : nullptr;

    conv_gelu_mfma<<<dim3(H_DIM, L_DIM / 1024), 256, 0, stream>>>(u, k, D, g, W, Wb);
    if (prew)
        pointwise_mfma<true><<<dim3(L_DIM / 128, H_DIM / 256, B_DIM), 256, 0, stream>>>(g, Wb, W, bias, out);
    else
        pointwise_mfma<false><<<dim3(L_DIM / 128, H_DIM / 256, B_DIM), 256, 0, stream>>>(g, nullptr, W, bias, out);
}

// Round 5
// 250.952 us; speedup vs baseline: 1.0658x; 1.0658x over previous
//
#include <hip/hip_runtime.h>
#include <hip/hip_bf16.h>
#include <math.h>

#define L_DIM 4096
#define H_DIM 512
#define B_DIM 8
#define SEG 2048

typedef __attribute__((ext_vector_type(8))) short short8;
typedef __attribute__((ext_vector_type(4))) float floatx4;

__device__ __forceinline__ unsigned f2bf(float f) {
    unsigned x = __float_as_uint(f);
    return (x + 0x7fffu + ((x >> 16) & 1u)) >> 16;   // RNE, finite inputs only
}

// ---------------------------------------------------------------------------
// Stage 1 (MFMA): causal Toeplitz conv + D-skip + exact GELU.
// Round-12: TLP instead of ILP. Rounds 9-11 proved the latency exposure is
// schedule-invariant at 12 waves/CU (3 different schedules, identical 22%
// MfmaUtil). The LDS footprint (k-images + u-window, 50.7KB) is per-
// (h, l-chunk), independent of wave count -> switch to 512-thread blocks
// (8 waves) covering a 2048-l chunk: same 3 blocks/CU but 24 waves/CU
// (6/SIMD; VGPR cap 85 >= the 68 this body needs). Pure stride scaling of
// the round-8 sliding-window body: t-stride 256, dd = 32c + 256(t+j),
// byte strides x2, j-shifts >>8. Per-lane fragment layout and the kA/kB
// parity trick untouched.
// ---------------------------------------------------------------------------
__global__ __launch_bounds__(512, 6) void conv_gelu_mfma(
    const float* __restrict__ u,    // (B,H,L) fp32
    const float* __restrict__ kk,   // (C=1,H,L) fp32
    const float* __restrict__ Dp,   // (H) fp32
    unsigned short* __restrict__ g, // (B,H,L) bf16 out (workspace)
    const float* __restrict__ W,    // (H,H) fp32
    unsigned short* __restrict__ Wb)// (H,H) bf16 out (workspace tail), may be null
{
    __shared__ __align__(16) unsigned short kA[4144];
    __shared__ __align__(16) unsigned short kB[4144];
    __shared__ __align__(16) unsigned short us[8][2104];

    const int h   = blockIdx.x;
    const int Lb  = blockIdx.y << 11;        // l-chunk base (2048 per block)
    const int tid = threadIdx.x;
    const int lane = tid & 63;
    const int w   = tid >> 6;                // wave id 0..7
    const int i   = lane & 15;               // A-row / C-col index
    const int q   = lane >> 4;               // quad
    const int b   = i & 7;                   // batch   (C-col decode)
    const int s   = i >> 3;                  // l-tile  (C-col decode)

    // one-time W fp32 -> bf16 conversion (coalesced, one row per h-block)
    if (Wb != nullptr && blockIdx.y == 0) {
        const float* wsrc = W + (size_t)h * H_DIM;
        unsigned short* wdst = Wb + (size_t)h * H_DIM;
        wdst[tid] = (unsigned short)f2bf(wsrc[tid]);
    }

    const float* kh = kk + (size_t)h * L_DIM;

    for (int p = tid; p < 4144; p += 512) {
        int t1 = L_DIM + 15 - p;
        int t2 = L_DIM + 14 - p;
        float v1 = (t1 >= 0 && t1 < L_DIM) ? kh[t1] : 0.0f;
        float v2 = (t2 >= 0 && t2 < L_DIM) ? kh[t2] : 0.0f;
        kA[p] = (unsigned short)f2bf(v1);
        kB[p] = (unsigned short)f2bf(v2);
    }

    floatx4 acc[8];
    #pragma unroll
    for (int t = 0; t < 8; t++) acc[t] = (floatx4){0.f, 0.f, 0.f, 0.f};

    const char* kbase = (const char*)((i & 1) ? kA : kB);
    const int aconst = 2 * (L_DIM + ((i & 1) ? 15 : 14) - i + 8 * q);
    const int basew = Lb + 32 * w;           // l0(t) = basew + 256*t

    union AFrag { int x[4]; short8 v; };

    for (int seg = 0; seg < 2; seg++) {
        const int ms = seg * SEG;
        const int mstart = (seg == 0) ? -32 : SEG;
        const int segmax = ms + SEG - 32;
        if (seg == 1) {
            // max m0 any wave needs = basew_max + 256*7 = Lb + 2016
            if (Lb + 2016 < SEG) break;      // uniform per block
            __syncthreads();                 // protect us[] until seg-0 compute done
        }
        for (int e = tid * 4; e < 2096; e += 2048) {
            int m = ms - 32 + e;
            #pragma unroll
            for (int bb = 0; bb < 8; bb++) {
                float4 v = make_float4(0.f, 0.f, 0.f, 0.f);
                if (m >= 0 && m < L_DIM)
                    v = *(const float4*)(u + ((size_t)bb * H_DIM + h) * L_DIM + m);
                unsigned lo = f2bf(v.x) | (f2bf(v.y) << 16);
                unsigned hi = f2bf(v.z) | (f2bf(v.w) << 16);
                *(uint2*)&us[bb][e] = make_uint2(lo, hi);
            }
        }
        __syncthreads();

        const char* bbase = (const char*)&us[b][0] + 2 * (32 - ms + 16 * s + 8 * q);
        const char* ab = kbase + aconst;     // A-frag address at dd = 0

        for (int c = 0; c < 8; c++) {
            const int c32 = 32 * c;
            const int rel = basew - c32;
            // m0(j) = rel - 256*j must lie in [mstart, segmax]
            const int j_hi = (rel - mstart) >> 8;            // floor div
            int j_lo = (rel - segmax + 255) >> 8;            // ceil div
            if (j_lo < -7) j_lo = -7;                        // t<=7 bound
            if (j_hi < j_lo) continue;
            const int n = j_hi - j_lo + 1;

            AFrag Wd[8];
            // preload slots d=1..7: sigma = j_hi + d, dd = c32 + 256*sigma <= 4096
            #pragma unroll
            for (int d = 1; d < 8; d++) {
                const int dd = c32 + (j_hi + d) * 256;
                if (dd >= 0) {
                    const int* ap = (const int*)(ab - 2 * dd);
                    Wd[d].x[0] = ap[0]; Wd[d].x[1] = ap[1];
                    Wd[d].x[2] = ap[2]; Wd[d].x[3] = ap[3];
                } else {
                    Wd[d].x[0] = 0; Wd[d].x[1] = 0; Wd[d].x[2] = 0; Wd[d].x[3] = 0;
                }
            }

            const char* aab = ab - 2 * c32 - 512 * j_hi;     // +512*jj -> frag at j=j_hi-jj
            const char* bb0 = bbase + 2 * (rel - 256 * j_hi);// +512*jj -> B at m0(j)

            for (int jb = 0; jb < n; jb += 8) {
                #pragma unroll
                for (int k = 0; k < 8; k++) {
                    const int jj = jb + k;
                    if (jj < n) {
                        const int dd0 = c32 + (j_hi - jj) * 256;
                        AFrag nf;
                        if (dd0 >= 0) {
                            const int* ap = (const int*)(aab + 512 * jj);
                            nf.x[0] = ap[0]; nf.x[1] = ap[1];
                            nf.x[2] = ap[2]; nf.x[3] = ap[3];
                        } else {
                            // non-causal diagonal: zero frag -> MFMA adds 0
                            nf.x[0] = 0; nf.x[1] = 0; nf.x[2] = 0; nf.x[3] = 0;
                        }
                        Wd[(8 - k) & 7] = nf;                // slot (-jj)&7, static
                        short8 bf = *(const short8*)(bb0 + 512 * jj);
                        #pragma unroll
                        for (int t = 0; t < 8; t++)
                            acc[t] = __builtin_amdgcn_mfma_f32_16x16x32_bf16(
                                Wd[(t - k) & 7].v, bf, acc[t], 0, 0, 0);
                    }
                }
            }
        }
    }

    const float Dh = Dp[h];
    #pragma unroll
    for (int t = 0; t < 8; t++) {
        const int l0 = Lb + 32 * w + 256 * t;
        const int lb2 = l0 + 16 * s + 4 * q;          // C/D: row = 4q + r, col = (b,s)
        const size_t off = ((size_t)b * H_DIM + h) * L_DIM + lb2;
        float4 uv = *(const float4*)(u + off);
        float y0 = acc[t][0] + uv.x * Dh;
        float y1 = acc[t][1] + uv.y * Dh;
        float y2 = acc[t][2] + uv.z * Dh;
        float y3 = acc[t][3] + uv.w * Dh;
        const float c = 0.70710678118654752f;
        float g0 = 0.5f * y0 * (1.0f + erff(y0 * c));
        float g1 = 0.5f * y1 * (1.0f + erff(y1 * c));
        float g2 = 0.5f * y2 * (1.0f + erff(y2 * c));
        float g3 = 0.5f * y3 * (1.0f + erff(y3 * c));
        unsigned lo = f2bf(g0) | (f2bf(g1) << 16);
        unsigned hi = f2bf(g2) | (f2bf(g3) << 16);
        *(uint2*)(g + off) = make_uint2(lo, hi);
    }
}

// ---------------------------------------------------------------------------
// Stage 2 (MFMA v2): out[b,d,l] = sum_c W[d,c]*g[b,c,l] + bias[d], fp32 out.
// Round-12: T14 async-stage split (PREW path). Old structure serialized
// {global load -> LDS write -> sync -> compute -> sync} per c0 -> ~600cy
// load latency fully exposed 8x. New: issue iteration it+1's 12 dwordx4
// loads BEFORE compute(it), pinned by sched_barrier(0) so they can't sink;
// LDS writes happen after the post-compute barrier. Load latency hides
// under 64 MFMAs + LDS reads. ws stride 76 (conflict-free) kept.
// ---------------------------------------------------------------------------
template <bool PREW>
__global__ __launch_bounds__(256, 2) void pointwise_mfma(
    const unsigned short* __restrict__ g,  // (B,H,L) bf16 (workspace)
    const unsigned short* __restrict__ Wb, // (H,H) bf16 (workspace tail) if PREW
    const float* __restrict__ W,           // (H,H) fp32 row-major [d][c]
    const float* __restrict__ bias,        // (H) fp32
    float* __restrict__ out)               // (B,H,L) fp32
{
    __shared__ __align__(16) unsigned gs2[128 * 36];        // 18432 B
    __shared__ __align__(16) unsigned short ws[256 * 76];   // 38912 B

    const int tid = threadIdx.x;
    const int l0 = blockIdx.x * 128;
    const int d0 = blockIdx.y * 256;
    const int bz = blockIdx.z;
    const int w  = tid >> 6;
    const int lane = tid & 63;
    const int n  = lane & 15;      // MFMA row/col lane index
    const int q  = lane >> 4;      // quad

    const int p   = tid & 31;      // c-pair column for g staging
    const int oct = tid >> 5;      // l-16-group 0..7 for g staging

    const int quarter = tid & 3;   // c-quarter for W staging
    const int rb      = tid >> 2;  // d-row base 0..63 for W staging

    floatx4 acc[8][4];
    #pragma unroll
    for (int mt = 0; mt < 8; mt++)
        #pragma unroll
        for (int nt = 0; nt < 4; nt++) acc[mt][nt] = (floatx4){0.f, 0.f, 0.f, 0.f};

    if (PREW) {
        const unsigned short* gbase = g + ((size_t)bz * H_DIM + 2 * p) * L_DIM + l0 + 16 * oct;
        const unsigned short* wbase = Wb + (size_t)(d0 + rb) * H_DIM + 16 * quarter;

        uint4 ga0, ga1, gb0, gb1;
        uint4 w00, w01, w10, w11, w20, w21, w30, w31;

        auto loadT = [&](int c0) {
            const unsigned short* gp = gbase + (size_t)c0 * L_DIM;
            ga0 = *(const uint4*)gp;
            ga1 = *(const uint4*)(gp + 8);
            gb0 = *(const uint4*)(gp + L_DIM);
            gb1 = *(const uint4*)(gp + L_DIM + 8);
            const unsigned short* wp = wbase + c0;
            w00 = ((const uint4*)wp)[0]; w01 = ((const uint4*)wp)[1]; wp += 64 * H_DIM;
            w10 = ((const uint4*)wp)[0]; w11 = ((const uint4*)wp)[1]; wp += 64 * H_DIM;
            w20 = ((const uint4*)wp)[0]; w21 = ((const uint4*)wp)[1]; wp += 64 * H_DIM;
            w30 = ((const uint4*)wp)[0]; w31 = ((const uint4*)wp)[1];
        };
        auto writeT = [&]() {
            #pragma unroll
            for (int half = 0; half < 2; half++) {
                const unsigned* ua = (const unsigned*)(half ? &ga1 : &ga0);
                const unsigned* ub = (const unsigned*)(half ? &gb1 : &gb0);
                #pragma unroll
                for (int e = 0; e < 4; e++) {
                    unsigned lo16 = (ua[e] & 0xFFFFu) | (ub[e] << 16);      // l even
                    unsigned hi16 = (ua[e] >> 16) | (ub[e] & 0xFFFF0000u);  // l odd
                    const int lrow = 16 * oct + 8 * half + 2 * e;
                    gs2[lrow * 36 + p] = lo16;
                    gs2[(lrow + 1) * 36 + p] = hi16;
                }
            }
            *(uint4*)&ws[(rb      ) * 76 + 16 * quarter]     = w00;
            *(uint4*)&ws[(rb      ) * 76 + 16 * quarter + 8] = w01;
            *(uint4*)&ws[(rb +  64) * 76 + 16 * quarter]     = w10;
            *(uint4*)&ws[(rb +  64) * 76 + 16 * quarter + 8] = w11;
            *(uint4*)&ws[(rb + 128) * 76 + 16 * quarter]     = w20;
            *(uint4*)&ws[(rb + 128) * 76 + 16 * quarter + 8] = w21;
            *(uint4*)&ws[(rb + 192) * 76 + 16 * quarter]     = w30;
            *(uint4*)&ws[(rb + 192) * 76 + 16 * quarter + 8] = w31;
        };
        auto computeT = [&]() {
            #pragma unroll
            for (int ks = 0; ks < 2; ks++) {
                short8 bfr[4];
                #pragma unroll
                for (int nt = 0; nt < 4; nt++)
                    bfr[nt] = *(const short8*)&ws[(64 * w + 16 * nt + n) * 76 + 32 * ks + 8 * q];
                #pragma unroll
                for (int mt = 0; mt < 8; mt++) {
                    union { uint4 u4; short8 v; } af;
                    af.u4 = *(const uint4*)&gs2[(16 * mt + n) * 36 + 16 * ks + 4 * q];
                    #pragma unroll
                    for (int nt = 0; nt < 4; nt++)
                        acc[mt][nt] = __builtin_amdgcn_mfma_f32_16x16x32_bf16(af.v, bfr[nt], acc[mt][nt], 0, 0, 0);
                }
            }
        };

        loadT(0);
        writeT();
        __syncthreads();
        #pragma unroll
        for (int it = 0; it < 8; it++) {
            if (it < 7) loadT(64 * (it + 1));       // prefetch next tile
            __builtin_amdgcn_sched_barrier(0);      // loads may not sink below
            computeT();
            if (it < 7) {
                __syncthreads();                    // everyone done reading LDS
                writeT();                           // land prefetched tile
                __syncthreads();
            }
        }
    } else {
        for (int c0 = 0; c0 < H_DIM; c0 += 64) {
            {
                const unsigned short* gp = g + ((size_t)bz * H_DIM + c0 + 2 * p) * L_DIM + l0 + 16 * oct;
                uint4 va0 = *(const uint4*)gp;
                uint4 va1 = *(const uint4*)(gp + 8);
                uint4 vb0 = *(const uint4*)(gp + L_DIM);
                uint4 vb1 = *(const uint4*)(gp + L_DIM + 8);
                #pragma unroll
                for (int half = 0; half < 2; half++) {
                    const unsigned* ua = (const unsigned*)(half ? &va1 : &va0);
                    const unsigned* ub = (const unsigned*)(half ? &vb1 : &vb0);
                    #pragma unroll
                    for (int e = 0; e < 4; e++) {
                        unsigned w0 = (ua[e] & 0xFFFFu) | (ub[e] << 16);
                        unsigned w1 = (ua[e] >> 16) | (ub[e] & 0xFFFF0000u);
                        const int lrow = 16 * oct + 8 * half + 2 * e;
                        gs2[lrow * 36 + p] = w0;
                        gs2[(lrow + 1) * 36 + p] = w1;
                    }
                }
            }
            {
                #pragma unroll
                for (int gg = 0; gg < 4; gg++) {
                    const int row = rb + 64 * gg;
                    const float* wp = W + (size_t)(d0 + row) * H_DIM + c0 + 16 * quarter;
                    float4 f0 = ((const float4*)wp)[0];
                    float4 f1 = ((const float4*)wp)[1];
                    float4 f2 = ((const float4*)wp)[2];
                    float4 f3 = ((const float4*)wp)[3];
                    unsigned o0 = f2bf(f0.x) | (f2bf(f0.y) << 16);
                    unsigned o1 = f2bf(f0.z) | (f2bf(f0.w) << 16);
                    unsigned o2 = f2bf(f1.x) | (f2bf(f1.y) << 16);
                    unsigned o3 = f2bf(f1.z) | (f2bf(f1.w) << 16);
                    unsigned o4 = f2bf(f2.x) | (f2bf(f2.y) << 16);
                    unsigned o5 = f2bf(f2.z) | (f2bf(f2.w) << 16);
                    unsigned o6 = f2bf(f3.x) | (f2bf(f3.y) << 16);
                    unsigned o7 = f2bf(f3.z) | (f2bf(f3.w) << 16);
                    *(uint4*)&ws[row * 76 + 16 * quarter]     = make_uint4(o0, o1, o2, o3);
                    *(uint4*)&ws[row * 76 + 16 * quarter + 8] = make_uint4(o4, o5, o6, o7);
                }
            }
            __syncthreads();
            #pragma unroll
            for (int ks = 0; ks < 2; ks++) {
                short8 bfr[4];
                #pragma unroll
                for (int nt = 0; nt < 4; nt++)
                    bfr[nt] = *(const short8*)&ws[(64 * w + 16 * nt + n) * 76 + 32 * ks + 8 * q];
                #pragma unroll
                for (int mt = 0; mt < 8; mt++) {
                    union { uint4 u4; short8 v; } af;
                    af.u4 = *(const uint4*)&gs2[(16 * mt + n) * 36 + 16 * ks + 4 * q];
                    #pragma unroll
                    for (int nt = 0; nt < 4; nt++)
                        acc[mt][nt] = __builtin_amdgcn_mfma_f32_16x16x32_bf16(af.v, bfr[nt], acc[mt][nt], 0, 0, 0);
                }
            }
            __syncthreads();
        }
    }

    // ---- epilogue: bias + coalesced float4 stores (4 consecutive l per lane)
    #pragma unroll
    for (int nt = 0; nt < 4; nt++) {
        const int d = d0 + 64 * w + 16 * nt + n;
        const float bb = bias[d];
        float* obase = out + ((size_t)bz * H_DIM + d) * L_DIM + l0 + 4 * q;
        #pragma unroll
        for (int mt = 0; mt < 8; mt++) {
            float4 r = make_float4(acc[mt][nt][0] + bb, acc[mt][nt][1] + bb,
                                   acc[mt][nt][2] + bb, acc[mt][nt][3] + bb);
            *(float4*)(obase + 16 * mt) = r;
        }
    }
}

extern "C" void kernel_launch(void* const* d_in, const int* in_sizes, int n_in,
                              void* d_out, int out_size, void* d_ws, size_t ws_size,
                              hipStream_t stream) {
    const float* u    = (const float*)d_in[0]; // (B,H,L)
    const float* k    = (const float*)d_in[1]; // (C,H,L) C=1
    const float* D    = (const float*)d_in[2]; // (C,H)
    const float* W    = (const float*)d_in[3]; // (H,C*H)
    const float* bias = (const float*)d_in[4]; // (H)
    float* out = (float*)d_out;
    unsigned short* g = (unsigned short*)d_ws;  // (B,H,L) bf16 intermediate, 32 MiB

    const size_t g_bytes = (size_t)B_DIM * H_DIM * L_DIM * sizeof(unsigned short); // 32 MiB
    const size_t w_bytes = (size_t)H_DIM * H_DIM * sizeof(unsigned short);         // 512 KiB
    const bool prew = ws_size >= g_bytes + w_bytes;
    unsigned short* Wb = prew ? (unsigned short*)((char*)d_ws + g_bytes) : nullptr;

    conv_gelu_mfma<<<dim3(H_DIM, L_DIM / 2048), 512, 0, stream>>>(u, k, D, g, W, Wb);
    if (prew)
        pointwise_mfma<true><<<dim3(L_DIM / 128, H_DIM / 256, B_DIM), 256, 0, stream>>>(g, Wb, W, bias, out);
    else
        pointwise_mfma<false><<<dim3(L_DIM / 128, H_DIM / 256, B_DIM), 256, 0, stream>>>(g, nullptr, W, bias, out);
}